// Round 7
// baseline (147.442 us; speedup 1.0000x reference)
//
#include <hip/hip_runtime.h>
#include <hip/hip_bf16.h>
#include <math.h>

#define B_   256
#define D1_  512
#define T_   256
#define O1_  256
#define O2_  128
#define OT   128

typedef __attribute__((ext_vector_type(8))) _Float16 f16x8;
typedef __attribute__((ext_vector_type(2))) _Float16 f16x2;
typedef __attribute__((ext_vector_type(4))) float f32x4;

// pack two floats -> two fp16 (RNE) in a u32 (low half = a)
__device__ inline unsigned pkh2(float a, float b) {
    union { f16x2 h; unsigned u; } c;
    c.h.x = (_Float16)a; c.h.y = (_Float16)b;
    return c.u;
}

// hi/lo fp16 split of 4 floats: hi = rne(v), lo = rne(v - hi)
__device__ inline void splith4(float v0, float v1, float v2, float v3,
                               uint2& hp, uint2& lp) {
    _Float16 h0 = (_Float16)v0, h1 = (_Float16)v1;
    _Float16 h2 = (_Float16)v2, h3 = (_Float16)v3;
    float r0 = v0 - (float)h0, r1 = v1 - (float)h1;
    float r2 = v2 - (float)h2, r3 = v3 - (float)h3;
    union { f16x2 h; unsigned u; } c;
    c.h.x = h0; c.h.y = h1; hp.x = c.u;
    c.h.x = h2; c.h.y = h3; hp.y = c.u;
    lp.x = pkh2(r0, r1); lp.y = pkh2(r2, r3);
}

// hi-only convert of 4 floats -> uint2 (4 fp16)
__device__ inline uint2 cvth4(float v0, float v1, float v2, float v3) {
    uint2 r; r.x = pkh2(v0, v1); r.y = pkh2(v2, v3); return r;
}

// 8 floats (two float4) -> fp16x8 fragment (hi only, in-register)
__device__ inline f16x8 cvt8h(float4 a, float4 b) {
    f16x8 r;
    r[0] = (_Float16)a.x; r[1] = (_Float16)a.y;
    r[2] = (_Float16)a.z; r[3] = (_Float16)a.w;
    r[4] = (_Float16)b.x; r[5] = (_Float16)b.y;
    r[6] = (_Float16)b.z; r[7] = (_Float16)b.w;
    return r;
}

// 16B fragment from 72-B-strided staging rows (two ds_read_b64)
__device__ inline f16x8 ld16(const char* p) {
    union { uint2 a[2]; f16x8 v; } f;
    f.a[0] = *(const uint2*)p;
    f.a[1] = *(const uint2*)(p + 8);
    return f.v;
}
__device__ inline f16x8 ldb128(const char* p) { return *(const f16x8*)p; }

#define MFMAH __builtin_amdgcn_mfma_f32_16x16x32_f16

// OT=128 o-rows per block, 1024 threads (16 waves, 4m x 4n), 1 block/CU.
// Pipeline per K-chunk (ONE barrier): write-arrived -> issue-2-ahead -> MFMA.
__global__ __launch_bounds__(1024, 4) void tabl_mfma(
    const float* __restrict__ x, const float* __restrict__ W1,
    const float* __restrict__ W, const float* __restrict__ W2,
    const float* __restrict__ alpha, const float* __restrict__ bias,
    float* __restrict__ out)
{
    __shared__ __align__(16) char Eh[OT * 512];        // E-hi / blended-hi, XOR-swizzled
    __shared__ __align__(16) char Bst[2][2][256 * 72]; // [buf][plane hi/lo]
    __shared__ float redm[4][OT];
    __shared__ float reds[4][OT];

    const int tid    = threadIdx.x;
    const int lane16 = tid & 15;
    const int lg     = (tid >> 4) & 3;
    const int wid    = tid >> 6;          // 0..15
    const int wm     = wid >> 2;          // 0..3
    const int wn     = wid & 3;           // 0..3

    // XCD swizzle: both o-halves of a batch land on the same XCD.
    const int bi  = blockIdx.x;
    const int xcd = bi & 7, q = bi >> 3;
    const int b     = xcd + (q >> 1) * 8;
    const int obase = (q & 1) * OT;

    // staging roles
    const int xs_t = tid & 255;           // staged row (t or s)
    const int koct = tid >> 8;            // 0..3 (8 k each)
    const int stO  = xs_t * 72 + koct * 16;
    const int zs = tid & 127, zoct = (tid >> 7) & 7;   // stage-3: 4 k each
    const int stZ  = zs * 72 + zoct * 8;

    // fragment offsets
    const int rArow[2] = { obase + wm * 32 + lane16, obase + wm * 32 + 16 + lane16 };
    const int eR[2]    = { wm * 32 + lane16, wm * 32 + 16 + lane16 };
    const int eBase[2] = { eR[0] * 512, eR[1] * 512 };
    const int eSw[2]   = { (eR[0] & 7) << 4, (eR[1] & 7) << 4 };
    int bOff[4], b3Off[2];
    #pragma unroll
    for (int nt = 0; nt < 4; ++nt) bOff[nt] = (wn * 64 + nt * 16 + lane16) * 72 + lg * 16;
    #pragma unroll
    for (int nt = 0; nt < 2; ++nt) b3Off[nt] = (wn * 32 + nt * 16 + lane16) * 72 + lg * 16;

    // ================= Stage 1: E = W1h @ (xh + xl)  (2-term fp16) =================
    f32x4 Eacc[2][4];
    #pragma unroll
    for (int mt = 0; mt < 2; ++mt)
        #pragma unroll
        for (int nt = 0; nt < 4; ++nt) Eacc[mt][nt] = (f32x4){0.f,0.f,0.f,0.f};

    const float* xcol = x + (size_t)b * (D1_ * T_) + xs_t;
    float xrN[8]; float4 apfC[2][2], apfN[2][2];

    { // prologue: chunk0 -> buf0 (direct), chunk1 -> xrN, A chunk0 -> apfC
        float x0[8];
        #pragma unroll
        for (int j = 0; j < 8; ++j) x0[j] = xcol[(size_t)(koct * 8 + j) * T_];
        #pragma unroll
        for (int mt = 0; mt < 2; ++mt) {
            const float4* ap = (const float4*)(W1 + (size_t)rArow[mt] * D1_ + lg * 8);
            apfC[mt][0] = ap[0]; apfC[mt][1] = ap[1];
        }
        #pragma unroll
        for (int j = 0; j < 8; ++j) xrN[j] = xcol[(size_t)(32 + koct * 8 + j) * T_];
        uint2 hp, lp;
        splith4(x0[0],x0[1],x0[2],x0[3],hp,lp);
        *(uint2*)(Bst[0][0] + stO) = hp; *(uint2*)(Bst[0][1] + stO) = lp;
        splith4(x0[4],x0[5],x0[6],x0[7],hp,lp);
        *(uint2*)(Bst[0][0] + stO + 8) = hp; *(uint2*)(Bst[0][1] + stO + 8) = lp;
    }
    __syncthreads();

    #pragma unroll 2
    for (int c = 0; c < 16; ++c) {
        const int cur = c & 1;
        // (1) convert+write chunk c+1 (data arrived a full chunk ago)
        if (c < 15) {
            uint2 hp, lp;
            splith4(xrN[0],xrN[1],xrN[2],xrN[3],hp,lp);
            *(uint2*)(Bst[cur^1][0] + stO) = hp; *(uint2*)(Bst[cur^1][1] + stO) = lp;
            splith4(xrN[4],xrN[5],xrN[6],xrN[7],hp,lp);
            *(uint2*)(Bst[cur^1][0] + stO + 8) = hp; *(uint2*)(Bst[cur^1][1] + stO + 8) = lp;
        }
        // (2) issue x loads two chunks ahead
        if (c < 14) {
            #pragma unroll
            for (int j = 0; j < 8; ++j)
                xrN[j] = xcol[(size_t)((c + 2) * 32 + koct * 8 + j) * T_];
        }
        // (3) A fragments for this chunk; issue A loads for c+1
        f16x8 Ah[2];
        #pragma unroll
        for (int mt = 0; mt < 2; ++mt) Ah[mt] = cvt8h(apfC[mt][0], apfC[mt][1]);
        if (c < 15) {
            #pragma unroll
            for (int mt = 0; mt < 2; ++mt) {
                const float4* ap = (const float4*)(W1 + (size_t)rArow[mt] * D1_ + (c + 1) * 32 + lg * 8);
                apfN[mt][0] = ap[0]; apfN[mt][1] = ap[1];
            }
        }
        // (4) B fragments + MFMA
        __builtin_amdgcn_s_setprio(1);
        #pragma unroll
        for (int np = 0; np < 2; ++np) {
            f16x8 Bh[2], Bl[2];
            #pragma unroll
            for (int h = 0; h < 2; ++h) {
                Bh[h] = ld16(Bst[cur][0] + bOff[np * 2 + h]);
                Bl[h] = ld16(Bst[cur][1] + bOff[np * 2 + h]);
            }
            #pragma unroll
            for (int mt = 0; mt < 2; ++mt)
                #pragma unroll
                for (int h = 0; h < 2; ++h) {
                    Eacc[mt][np*2+h] = MFMAH(Ah[mt], Bh[h], Eacc[mt][np*2+h], 0,0,0);
                    Eacc[mt][np*2+h] = MFMAH(Ah[mt], Bl[h], Eacc[mt][np*2+h], 0,0,0);
                }
        }
        __builtin_amdgcn_s_setprio(0);
        #pragma unroll
        for (int mt = 0; mt < 2; ++mt) {
            apfC[mt][0] = apfN[mt][0]; apfC[mt][1] = apfN[mt][1];
        }
        __syncthreads();
    }

    // write E-hi (fp16) to LDS for stage-2/3 A fragments (E stays in regs for blend)
    #pragma unroll
    for (int mt = 0; mt < 2; ++mt)
        #pragma unroll
        for (int nt = 0; nt < 4; ++nt)
            #pragma unroll
            for (int i = 0; i < 4; ++i) {
                int r = wm * 32 + mt * 16 + lg * 4 + i;
                int t = wn * 64 + nt * 16 + lane16;
                union { _Float16 h; unsigned short u; } cc;
                cc.h = (_Float16)Eacc[mt][nt][i];
                *(unsigned short*)(Eh + r * 512 + ((2 * t) ^ ((r & 7) << 4))) = cc.u;
            }

    // ================= Stage 2: S = Eh @ Wh  (fp16 hi-only) =================
    f32x4 Sacc[2][4];
    #pragma unroll
    for (int mt = 0; mt < 2; ++mt)
        #pragma unroll
        for (int nt = 0; nt < 4; ++nt) Sacc[mt][nt] = (f32x4){0.f,0.f,0.f,0.f};

    const float* wcol = W + xs_t;
    float wrN[8];
    { // prologue: chunk0 -> buf0, chunk1 -> wrN
        float w0[8];
        #pragma unroll
        for (int j = 0; j < 8; ++j) w0[j] = wcol[(size_t)(koct * 8 + j) * T_];
        #pragma unroll
        for (int j = 0; j < 8; ++j) wrN[j] = wcol[(size_t)(32 + koct * 8 + j) * T_];
        *(uint2*)(Bst[0][0] + stO)     = cvth4(w0[0],w0[1],w0[2],w0[3]);
        *(uint2*)(Bst[0][0] + stO + 8) = cvth4(w0[4],w0[5],w0[6],w0[7]);
    }
    __syncthreads();   // also covers E-hi writes before A reads

    #pragma unroll 2
    for (int c = 0; c < 8; ++c) {
        const int cur = c & 1;
        if (c < 7) {
            *(uint2*)(Bst[cur^1][0] + stO)     = cvth4(wrN[0],wrN[1],wrN[2],wrN[3]);
            *(uint2*)(Bst[cur^1][0] + stO + 8) = cvth4(wrN[4],wrN[5],wrN[6],wrN[7]);
        }
        if (c < 6) {
            #pragma unroll
            for (int j = 0; j < 8; ++j)
                wrN[j] = wcol[(size_t)((c + 2) * 32 + koct * 8 + j) * T_];
        }
        f16x8 Af[2];
        #pragma unroll
        for (int mt = 0; mt < 2; ++mt)
            Af[mt] = ldb128(Eh + eBase[mt] + ((c * 64 + lg * 16) ^ eSw[mt]));
        __builtin_amdgcn_s_setprio(1);
        #pragma unroll
        for (int np = 0; np < 2; ++np) {
            f16x8 Bf[2];
            #pragma unroll
            for (int h = 0; h < 2; ++h) Bf[h] = ld16(Bst[cur][0] + bOff[np * 2 + h]);
            #pragma unroll
            for (int mt = 0; mt < 2; ++mt)
                #pragma unroll
                for (int h = 0; h < 2; ++h)
                    Sacc[mt][np*2+h] = MFMAH(Af[mt], Bf[h], Sacc[mt][np*2+h], 0,0,0);
        }
        __builtin_amdgcn_s_setprio(0);
        __syncthreads();
    }

    // ============ row softmax over s (cross-wave) + blend -> Eh ============
    const float a_ = alpha[0];
    float pm[2][4];
    #pragma unroll
    for (int mt = 0; mt < 2; ++mt)
        #pragma unroll
        for (int i = 0; i < 4; ++i) {
            float m = fmaxf(fmaxf(Sacc[mt][0][i], Sacc[mt][1][i]),
                            fmaxf(Sacc[mt][2][i], Sacc[mt][3][i]));
            m = fmaxf(m, __shfl_xor(m, 1));
            m = fmaxf(m, __shfl_xor(m, 2));
            m = fmaxf(m, __shfl_xor(m, 4));
            m = fmaxf(m, __shfl_xor(m, 8));
            float s = 0.f;
            #pragma unroll
            for (int nt = 0; nt < 4; ++nt) {
                float p = __expf(Sacc[mt][nt][i] - m);
                Sacc[mt][nt][i] = p; s += p;
            }
            s += __shfl_xor(s, 1);
            s += __shfl_xor(s, 2);
            s += __shfl_xor(s, 4);
            s += __shfl_xor(s, 8);
            pm[mt][i] = m;
            if (lane16 == 0) {
                int r = wm * 32 + mt * 16 + lg * 4 + i;
                redm[wn][r] = m; reds[wn][r] = s;
            }
        }
    // issue W2 chunk-0/1 loads (hide under softmax finish)
    float zr0[4], zrN[4];
    #pragma unroll
    for (int j = 0; j < 4; ++j) zr0[j] = W2[(size_t)(zoct * 4 + j) * O2_ + zs];
    #pragma unroll
    for (int j = 0; j < 4; ++j) zrN[j] = W2[(size_t)(32 + zoct * 4 + j) * O2_ + zs];
    __syncthreads();

    #pragma unroll
    for (int mt = 0; mt < 2; ++mt)
        #pragma unroll
        for (int i = 0; i < 4; ++i) {
            int r = wm * 32 + mt * 16 + lg * 4 + i;
            float M = fmaxf(fmaxf(redm[0][r], redm[1][r]),
                            fmaxf(redm[2][r], redm[3][r]));
            float den = reds[0][r] * __expf(redm[0][r] - M)
                      + reds[1][r] * __expf(redm[1][r] - M)
                      + reds[2][r] * __expf(redm[2][r] - M)
                      + reds[3][r] * __expf(redm[3][r] - M);
            float sc = __expf(pm[mt][i] - M) / den;
            #pragma unroll
            for (int nt = 0; nt < 4; ++nt) {
                float f = a_ + (1.f - a_) * Sacc[mt][nt][i] * sc;
                float v = Eacc[mt][nt][i] * f;
                int t = wn * 64 + nt * 16 + lane16;
                union { _Float16 h; unsigned short u; } cc;
                cc.h = (_Float16)v;
                *(unsigned short*)(Eh + r * 512 + ((2 * t) ^ ((r & 7) << 4))) = cc.u;
            }
        }
    { // W2 chunk 0 convert+write (hi only) -> buf0
        *(uint2*)(Bst[0][0] + stZ) = cvth4(zr0[0], zr0[1], zr0[2], zr0[3]);
    }
    __syncthreads();

    // ========== Stage 3: Y = blended_h @ W2h + bias (fp16 hi-only) ==========
    f32x4 Yacc[2][2];
    #pragma unroll
    for (int mt = 0; mt < 2; ++mt)
        #pragma unroll
        for (int nt = 0; nt < 2; ++nt) Yacc[mt][nt] = (f32x4){0.f,0.f,0.f,0.f};

    #pragma unroll 2
    for (int c = 0; c < 8; ++c) {
        const int cur = c & 1;
        if (c < 7) {
            *(uint2*)(Bst[cur^1][0] + stZ) = cvth4(zrN[0], zrN[1], zrN[2], zrN[3]);
        }
        if (c < 6) {
            #pragma unroll
            for (int j = 0; j < 4; ++j)
                zrN[j] = W2[(size_t)((c + 2) * 32 + zoct * 4 + j) * O2_ + zs];
        }
        f16x8 Ahf[2];
        #pragma unroll
        for (int mt = 0; mt < 2; ++mt)
            Ahf[mt] = ldb128(Eh + eBase[mt] + ((c * 64 + lg * 16) ^ eSw[mt]));
        __builtin_amdgcn_s_setprio(1);
        {
            f16x8 Bh[2];
            #pragma unroll
            for (int nt = 0; nt < 2; ++nt) Bh[nt] = ld16(Bst[cur][0] + b3Off[nt]);
            #pragma unroll
            for (int mt = 0; mt < 2; ++mt)
                #pragma unroll
                for (int nt = 0; nt < 2; ++nt)
                    Yacc[mt][nt] = MFMAH(Ahf[mt], Bh[nt], Yacc[mt][nt], 0,0,0);
        }
        __builtin_amdgcn_s_setprio(0);
        __syncthreads();
    }

    // epilogue: + bias, store pre-softmax Y
    #pragma unroll
    for (int mt = 0; mt < 2; ++mt)
        #pragma unroll
        for (int nt = 0; nt < 2; ++nt)
            #pragma unroll
            for (int i = 0; i < 4; ++i) {
                int o  = obase + wm * 32 + mt * 16 + lg * 4 + i;
                int s2 = wn * 32 + nt * 16 + lane16;
                out[((size_t)b * O1_ + o) * O2_ + s2] =
                    Yacc[mt][nt][i] + bias[(size_t)o * O2_ + s2];
            }
}

// in-place softmax over axis 1 (O1); one block per batch
__global__ __launch_bounds__(256) void softmax_o1(float* __restrict__ out)
{
    __shared__ float sm[2][128], ss[2][128];
    const int b  = blockIdx.x;
    const int s2 = threadIdx.x & 127;
    const int oh = threadIdx.x >> 7;
    float* p = out + (size_t)b * (O1_ * O2_) + s2;
    float m = -INFINITY, s = 0.f;
    #pragma unroll 4
    for (int o = oh * 128; o < oh * 128 + 128; ++o) {
        float v = p[(size_t)o * O2_];
        float mn = fmaxf(m, v);
        s = s * __expf(m - mn) + __expf(v - mn);
        m = mn;
    }
    sm[oh][s2] = m; ss[oh][s2] = s;
    __syncthreads();
    float M = fmaxf(sm[0][s2], sm[1][s2]);
    float S = ss[0][s2] * __expf(sm[0][s2] - M) + ss[1][s2] * __expf(sm[1][s2] - M);
    float inv = 1.f / S;
    #pragma unroll 4
    for (int o = oh * 128; o < oh * 128 + 128; ++o) {
        float v = p[(size_t)o * O2_];
        p[(size_t)o * O2_] = __expf(v - M) * inv;
    }
}

extern "C" void kernel_launch(void* const* d_in, const int* in_sizes, int n_in,
                              void* d_out, int out_size, void* d_ws, size_t ws_size,
                              hipStream_t stream)
{
    const float* x     = (const float*)d_in[0];
    const float* W1    = (const float*)d_in[1];
    const float* W     = (const float*)d_in[2];
    const float* W2    = (const float*)d_in[3];
    const float* alpha = (const float*)d_in[4];
    const float* bias  = (const float*)d_in[5];
    float* out = (float*)d_out;

    tabl_mfma<<<dim3(512), 1024, 0, stream>>>(x, W1, W, W2, alpha, bias, out);
    softmax_o1<<<B_, 256, 0, stream>>>(out);
}

// Round 8
// 140.635 us; speedup vs baseline: 1.0484x; 1.0484x over previous
//
#include <hip/hip_runtime.h>
#include <hip/hip_bf16.h>
#include <math.h>

#define B_   256
#define D1_  512
#define T_   256
#define O1_  256
#define O2_  128
#define OT   128

typedef __attribute__((ext_vector_type(8))) _Float16 f16x8;
typedef __attribute__((ext_vector_type(2))) _Float16 f16x2;
typedef __attribute__((ext_vector_type(4))) float f32x4;

// pack two floats -> two fp16 (RNE) in a u32 (low half = a)
__device__ inline unsigned pkh2(float a, float b) {
    union { f16x2 h; unsigned u; } c;
    c.h.x = (_Float16)a; c.h.y = (_Float16)b;
    return c.u;
}

// hi/lo fp16 split of 4 floats: hi = rne(v), lo = rne(v - hi)
__device__ inline void splith4(float v0, float v1, float v2, float v3,
                               uint2& hp, uint2& lp) {
    _Float16 h0 = (_Float16)v0, h1 = (_Float16)v1;
    _Float16 h2 = (_Float16)v2, h3 = (_Float16)v3;
    float r0 = v0 - (float)h0, r1 = v1 - (float)h1;
    float r2 = v2 - (float)h2, r3 = v3 - (float)h3;
    union { f16x2 h; unsigned u; } c;
    c.h.x = h0; c.h.y = h1; hp.x = c.u;
    c.h.x = h2; c.h.y = h3; hp.y = c.u;
    lp.x = pkh2(r0, r1); lp.y = pkh2(r2, r3);
}

// hi-only convert of 4 floats -> uint2 (4 fp16)
__device__ inline uint2 cvth4(float v0, float v1, float v2, float v3) {
    uint2 r; r.x = pkh2(v0, v1); r.y = pkh2(v2, v3); return r;
}

// 8 floats (two float4) -> fp16x8 fragment (hi only, in-register)
__device__ inline f16x8 cvt8h(float4 a, float4 b) {
    f16x8 r;
    r[0] = (_Float16)a.x; r[1] = (_Float16)a.y;
    r[2] = (_Float16)a.z; r[3] = (_Float16)a.w;
    r[4] = (_Float16)b.x; r[5] = (_Float16)b.y;
    r[6] = (_Float16)b.z; r[7] = (_Float16)b.w;
    return r;
}

// 16B fragment from 72-B-strided staging rows (two ds_read_b64)
__device__ inline f16x8 ld16(const char* p) {
    union { uint2 a[2]; f16x8 v; } f;
    f.a[0] = *(const uint2*)p;
    f.a[1] = *(const uint2*)(p + 8);
    return f.v;
}
__device__ inline f16x8 ldb128(const char* p) { return *(const f16x8*)p; }

#define MFMAH __builtin_amdgcn_mfma_f32_16x16x32_f16

// OT=128 o-rows per block, 1024 threads (16 waves, 4m x 4n), 1 block/CU.
// NO occupancy clamp: 16-wave block naturally allows up to 128 VGPR.
// Per K-chunk (ONE barrier): A-cvt/prefetch -> MFMA -> write-arrived -> issue-2-ahead.
__global__ __launch_bounds__(1024) void tabl_mfma(
    const float* __restrict__ x, const float* __restrict__ W1,
    const float* __restrict__ W, const float* __restrict__ W2,
    const float* __restrict__ alpha, const float* __restrict__ bias,
    float* __restrict__ out)
{
    __shared__ __align__(16) char Eh[OT * 512];        // E-hi / blended-hi, XOR-swizzled
    __shared__ __align__(16) char Bst[2][2][256 * 72]; // [buf][plane hi/lo]
    __shared__ float redm[4][OT];
    __shared__ float reds[4][OT];

    const int tid    = threadIdx.x;
    const int lane16 = tid & 15;
    const int lg     = (tid >> 4) & 3;
    const int wid    = tid >> 6;          // 0..15
    const int wm     = wid >> 2;          // 0..3
    const int wn     = wid & 3;           // 0..3

    // XCD swizzle: both o-halves of a batch land on the same XCD.
    const int bi  = blockIdx.x;
    const int xcd = bi & 7, q = bi >> 3;
    const int b     = xcd + (q >> 1) * 8;
    const int obase = (q & 1) * OT;

    // staging roles
    const int xs_t = tid & 255;           // staged row (t or s)
    const int koct = tid >> 8;            // 0..3 (8 k each)
    const int stO  = xs_t * 72 + koct * 16;
    const int zs = tid & 127, zoct = (tid >> 7) & 7;   // stage-3: 4 k each
    const int stZ  = zs * 72 + zoct * 8;

    // fragment offsets
    const int rArow[2] = { obase + wm * 32 + lane16, obase + wm * 32 + 16 + lane16 };
    const int eR[2]    = { wm * 32 + lane16, wm * 32 + 16 + lane16 };
    const int eBase[2] = { eR[0] * 512, eR[1] * 512 };
    const int eSw[2]   = { (eR[0] & 7) << 4, (eR[1] & 7) << 4 };
    int bOff[4], b3Off[2];
    #pragma unroll
    for (int nt = 0; nt < 4; ++nt) bOff[nt] = (wn * 64 + nt * 16 + lane16) * 72 + lg * 16;
    #pragma unroll
    for (int nt = 0; nt < 2; ++nt) b3Off[nt] = (wn * 32 + nt * 16 + lane16) * 72 + lg * 16;

    // ================= Stage 1: E = W1h @ (xh + xl)  (2-term fp16) =================
    f32x4 Eacc[2][4];
    #pragma unroll
    for (int mt = 0; mt < 2; ++mt)
        #pragma unroll
        for (int nt = 0; nt < 4; ++nt) Eacc[mt][nt] = (f32x4){0.f,0.f,0.f,0.f};

    const float* xcol = x + (size_t)b * (D1_ * T_) + xs_t;
    float xrN[8]; float4 apfC[2][2], apfN[2][2];

    { // prologue: chunk0 -> buf0 (direct), chunk1 -> xrN, A chunk0 -> apfC
        float x0[8];
        #pragma unroll
        for (int j = 0; j < 8; ++j) x0[j] = xcol[(size_t)(koct * 8 + j) * T_];
        #pragma unroll
        for (int mt = 0; mt < 2; ++mt) {
            const float4* ap = (const float4*)(W1 + (size_t)rArow[mt] * D1_ + lg * 8);
            apfC[mt][0] = ap[0]; apfC[mt][1] = ap[1];
        }
        #pragma unroll
        for (int j = 0; j < 8; ++j) xrN[j] = xcol[(size_t)(32 + koct * 8 + j) * T_];
        uint2 hp, lp;
        splith4(x0[0],x0[1],x0[2],x0[3],hp,lp);
        *(uint2*)(Bst[0][0] + stO) = hp; *(uint2*)(Bst[0][1] + stO) = lp;
        splith4(x0[4],x0[5],x0[6],x0[7],hp,lp);
        *(uint2*)(Bst[0][0] + stO + 8) = hp; *(uint2*)(Bst[0][1] + stO + 8) = lp;
    }
    __syncthreads();

    #pragma unroll 2
    for (int c = 0; c < 16; ++c) {
        const int cur = c & 1;
        // (1) A fragments for this chunk; issue A loads for c+1
        f16x8 Ah[2];
        #pragma unroll
        for (int mt = 0; mt < 2; ++mt) Ah[mt] = cvt8h(apfC[mt][0], apfC[mt][1]);
        if (c < 15) {
            #pragma unroll
            for (int mt = 0; mt < 2; ++mt) {
                const float4* ap = (const float4*)(W1 + (size_t)rArow[mt] * D1_ + (c + 1) * 32 + lg * 8);
                apfN[mt][0] = ap[0]; apfN[mt][1] = ap[1];
            }
        }
        // (2) B fragments + MFMA on buf[cur]
        __builtin_amdgcn_s_setprio(1);
        #pragma unroll
        for (int np = 0; np < 2; ++np) {
            f16x8 Bh[2], Bl[2];
            #pragma unroll
            for (int h = 0; h < 2; ++h) {
                Bh[h] = ld16(Bst[cur][0] + bOff[np * 2 + h]);
                Bl[h] = ld16(Bst[cur][1] + bOff[np * 2 + h]);
            }
            #pragma unroll
            for (int mt = 0; mt < 2; ++mt)
                #pragma unroll
                for (int h = 0; h < 2; ++h) {
                    Eacc[mt][np*2+h] = MFMAH(Ah[mt], Bh[h], Eacc[mt][np*2+h], 0,0,0);
                    Eacc[mt][np*2+h] = MFMAH(Ah[mt], Bl[h], Eacc[mt][np*2+h], 0,0,0);
                }
        }
        __builtin_amdgcn_s_setprio(0);
        // (3) convert+write chunk c+1 (data arrived a full chunk ago)
        if (c < 15) {
            uint2 hp, lp;
            splith4(xrN[0],xrN[1],xrN[2],xrN[3],hp,lp);
            *(uint2*)(Bst[cur^1][0] + stO) = hp; *(uint2*)(Bst[cur^1][1] + stO) = lp;
            splith4(xrN[4],xrN[5],xrN[6],xrN[7],hp,lp);
            *(uint2*)(Bst[cur^1][0] + stO + 8) = hp; *(uint2*)(Bst[cur^1][1] + stO + 8) = lp;
        }
        // (4) issue x loads two chunks ahead
        if (c < 14) {
            #pragma unroll
            for (int j = 0; j < 8; ++j)
                xrN[j] = xcol[(size_t)((c + 2) * 32 + koct * 8 + j) * T_];
        }
        #pragma unroll
        for (int mt = 0; mt < 2; ++mt) {
            apfC[mt][0] = apfN[mt][0]; apfC[mt][1] = apfN[mt][1];
        }
        __syncthreads();
    }

    // write E-hi (fp16) to LDS for stage-2/3 A fragments (E stays in regs for blend)
    #pragma unroll
    for (int mt = 0; mt < 2; ++mt)
        #pragma unroll
        for (int nt = 0; nt < 4; ++nt)
            #pragma unroll
            for (int i = 0; i < 4; ++i) {
                int r = wm * 32 + mt * 16 + lg * 4 + i;
                int t = wn * 64 + nt * 16 + lane16;
                union { _Float16 h; unsigned short u; } cc;
                cc.h = (_Float16)Eacc[mt][nt][i];
                *(unsigned short*)(Eh + r * 512 + ((2 * t) ^ ((r & 7) << 4))) = cc.u;
            }

    // ================= Stage 2: S = Eh @ Wh  (fp16 hi-only) =================
    f32x4 Sacc[2][4];
    #pragma unroll
    for (int mt = 0; mt < 2; ++mt)
        #pragma unroll
        for (int nt = 0; nt < 4; ++nt) Sacc[mt][nt] = (f32x4){0.f,0.f,0.f,0.f};

    const float* wcol = W + xs_t;
    float wrN[8];
    { // prologue: chunk0 -> buf0 (direct), chunk1 -> wrN
        float w0[8];
        #pragma unroll
        for (int j = 0; j < 8; ++j) w0[j] = wcol[(size_t)(koct * 8 + j) * T_];
        #pragma unroll
        for (int j = 0; j < 8; ++j) wrN[j] = wcol[(size_t)(32 + koct * 8 + j) * T_];
        *(uint2*)(Bst[0][0] + stO)     = cvth4(w0[0],w0[1],w0[2],w0[3]);
        *(uint2*)(Bst[0][0] + stO + 8) = cvth4(w0[4],w0[5],w0[6],w0[7]);
    }
    __syncthreads();   // also covers E-hi writes before A reads

    #pragma unroll 2
    for (int c = 0; c < 8; ++c) {
        const int cur = c & 1;
        f16x8 Af[2];
        #pragma unroll
        for (int mt = 0; mt < 2; ++mt)
            Af[mt] = ldb128(Eh + eBase[mt] + ((c * 64 + lg * 16) ^ eSw[mt]));
        __builtin_amdgcn_s_setprio(1);
        #pragma unroll
        for (int np = 0; np < 2; ++np) {
            f16x8 Bf[2];
            #pragma unroll
            for (int h = 0; h < 2; ++h) Bf[h] = ld16(Bst[cur][0] + bOff[np * 2 + h]);
            #pragma unroll
            for (int mt = 0; mt < 2; ++mt)
                #pragma unroll
                for (int h = 0; h < 2; ++h)
                    Sacc[mt][np*2+h] = MFMAH(Af[mt], Bf[h], Sacc[mt][np*2+h], 0,0,0);
        }
        __builtin_amdgcn_s_setprio(0);
        if (c < 7) {
            *(uint2*)(Bst[cur^1][0] + stO)     = cvth4(wrN[0],wrN[1],wrN[2],wrN[3]);
            *(uint2*)(Bst[cur^1][0] + stO + 8) = cvth4(wrN[4],wrN[5],wrN[6],wrN[7]);
        }
        if (c < 6) {
            #pragma unroll
            for (int j = 0; j < 8; ++j)
                wrN[j] = wcol[(size_t)((c + 2) * 32 + koct * 8 + j) * T_];
        }
        __syncthreads();
    }

    // ============ row softmax over s (cross-wave) + blend -> Eh ============
    const float a_ = alpha[0];
    float pm[2][4];
    #pragma unroll
    for (int mt = 0; mt < 2; ++mt)
        #pragma unroll
        for (int i = 0; i < 4; ++i) {
            float m = fmaxf(fmaxf(Sacc[mt][0][i], Sacc[mt][1][i]),
                            fmaxf(Sacc[mt][2][i], Sacc[mt][3][i]));
            m = fmaxf(m, __shfl_xor(m, 1));
            m = fmaxf(m, __shfl_xor(m, 2));
            m = fmaxf(m, __shfl_xor(m, 4));
            m = fmaxf(m, __shfl_xor(m, 8));
            float s = 0.f;
            #pragma unroll
            for (int nt = 0; nt < 4; ++nt) {
                float p = __expf(Sacc[mt][nt][i] - m);
                Sacc[mt][nt][i] = p; s += p;
            }
            s += __shfl_xor(s, 1);
            s += __shfl_xor(s, 2);
            s += __shfl_xor(s, 4);
            s += __shfl_xor(s, 8);
            pm[mt][i] = m;
            if (lane16 == 0) {
                int r = wm * 32 + mt * 16 + lg * 4 + i;
                redm[wn][r] = m; reds[wn][r] = s;
            }
        }
    // issue W2 chunk-0/1 loads (hide under softmax finish)
    float zr0[4], zrN[4];
    #pragma unroll
    for (int j = 0; j < 4; ++j) zr0[j] = W2[(size_t)(zoct * 4 + j) * O2_ + zs];
    #pragma unroll
    for (int j = 0; j < 4; ++j) zrN[j] = W2[(size_t)(32 + zoct * 4 + j) * O2_ + zs];
    __syncthreads();

    #pragma unroll
    for (int mt = 0; mt < 2; ++mt)
        #pragma unroll
        for (int i = 0; i < 4; ++i) {
            int r = wm * 32 + mt * 16 + lg * 4 + i;
            float M = fmaxf(fmaxf(redm[0][r], redm[1][r]),
                            fmaxf(redm[2][r], redm[3][r]));
            float den = reds[0][r] * __expf(redm[0][r] - M)
                      + reds[1][r] * __expf(redm[1][r] - M)
                      + reds[2][r] * __expf(redm[2][r] - M)
                      + reds[3][r] * __expf(redm[3][r] - M);
            float sc = __expf(pm[mt][i] - M) / den;
            #pragma unroll
            for (int nt = 0; nt < 4; ++nt) {
                float f = a_ + (1.f - a_) * Sacc[mt][nt][i] * sc;
                float v = Eacc[mt][nt][i] * f;
                int t = wn * 64 + nt * 16 + lane16;
                union { _Float16 h; unsigned short u; } cc;
                cc.h = (_Float16)v;
                *(unsigned short*)(Eh + r * 512 + ((2 * t) ^ ((r & 7) << 4))) = cc.u;
            }
        }
    { // W2 chunk 0 convert+write (hi only) -> buf0
        *(uint2*)(Bst[0][0] + stZ) = cvth4(zr0[0], zr0[1], zr0[2], zr0[3]);
    }
    __syncthreads();

    // ========== Stage 3: Y = blended_h @ W2h + bias (fp16 hi-only) ==========
    f32x4 Yacc[2][2];
    #pragma unroll
    for (int mt = 0; mt < 2; ++mt)
        #pragma unroll
        for (int nt = 0; nt < 2; ++nt) Yacc[mt][nt] = (f32x4){0.f,0.f,0.f,0.f};

    #pragma unroll 2
    for (int c = 0; c < 8; ++c) {
        const int cur = c & 1;
        f16x8 Ahf[2];
        #pragma unroll
        for (int mt = 0; mt < 2; ++mt)
            Ahf[mt] = ldb128(Eh + eBase[mt] + ((c * 64 + lg * 16) ^ eSw[mt]));
        __builtin_amdgcn_s_setprio(1);
        {
            f16x8 Bh[2];
            #pragma unroll
            for (int nt = 0; nt < 2; ++nt) Bh[nt] = ld16(Bst[cur][0] + b3Off[nt]);
            #pragma unroll
            for (int mt = 0; mt < 2; ++mt)
                #pragma unroll
                for (int nt = 0; nt < 2; ++nt)
                    Yacc[mt][nt] = MFMAH(Ahf[mt], Bh[nt], Yacc[mt][nt], 0,0,0);
        }
        __builtin_amdgcn_s_setprio(0);
        if (c < 7) {
            *(uint2*)(Bst[cur^1][0] + stZ) = cvth4(zrN[0], zrN[1], zrN[2], zrN[3]);
        }
        if (c < 6) {
            #pragma unroll
            for (int j = 0; j < 4; ++j)
                zrN[j] = W2[(size_t)((c + 2) * 32 + zoct * 4 + j) * O2_ + zs];
        }
        __syncthreads();
    }

    // epilogue: + bias, store pre-softmax Y
    #pragma unroll
    for (int mt = 0; mt < 2; ++mt)
        #pragma unroll
        for (int nt = 0; nt < 2; ++nt)
            #pragma unroll
            for (int i = 0; i < 4; ++i) {
                int o  = obase + wm * 32 + mt * 16 + lg * 4 + i;
                int s2 = wn * 32 + nt * 16 + lane16;
                out[((size_t)b * O1_ + o) * O2_ + s2] =
                    Yacc[mt][nt][i] + bias[(size_t)o * O2_ + s2];
            }
}

// in-place softmax over axis 1 (O1); one block per batch
__global__ __launch_bounds__(256) void softmax_o1(float* __restrict__ out)
{
    __shared__ float sm[2][128], ss[2][128];
    const int b  = blockIdx.x;
    const int s2 = threadIdx.x & 127;
    const int oh = threadIdx.x >> 7;
    float* p = out + (size_t)b * (O1_ * O2_) + s2;
    float m = -INFINITY, s = 0.f;
    #pragma unroll 4
    for (int o = oh * 128; o < oh * 128 + 128; ++o) {
        float v = p[(size_t)o * O2_];
        float mn = fmaxf(m, v);
        s = s * __expf(m - mn) + __expf(v - mn);
        m = mn;
    }
    sm[oh][s2] = m; ss[oh][s2] = s;
    __syncthreads();
    float M = fmaxf(sm[0][s2], sm[1][s2]);
    float S = ss[0][s2] * __expf(sm[0][s2] - M) + ss[1][s2] * __expf(sm[1][s2] - M);
    float inv = 1.f / S;
    #pragma unroll 4
    for (int o = oh * 128; o < oh * 128 + 128; ++o) {
        float v = p[(size_t)o * O2_];
        p[(size_t)o * O2_] = __expf(v - M) * inv;
    }
}

extern "C" void kernel_launch(void* const* d_in, const int* in_sizes, int n_in,
                              void* d_out, int out_size, void* d_ws, size_t ws_size,
                              hipStream_t stream)
{
    const float* x     = (const float*)d_in[0];
    const float* W1    = (const float*)d_in[1];
    const float* W     = (const float*)d_in[2];
    const float* W2    = (const float*)d_in[3];
    const float* alpha = (const float*)d_in[4];
    const float* bias  = (const float*)d_in[5];
    float* out = (float*)d_out;

    tabl_mfma<<<dim3(512), 1024, 0, stream>>>(x, W1, W, W2, alpha, bias, out);
    softmax_o1<<<B_, 256, 0, stream>>>(out);
}

// Round 9
// 140.237 us; speedup vs baseline: 1.0514x; 1.0028x over previous
//
#include <hip/hip_runtime.h>
#include <hip/hip_bf16.h>
#include <math.h>

#define B_   256
#define D1_  512
#define T_   256
#define O1_  256
#define O2_  128
#define OT   128

typedef __attribute__((ext_vector_type(8))) _Float16 f16x8;
typedef __attribute__((ext_vector_type(2))) _Float16 f16x2;
typedef __attribute__((ext_vector_type(4))) float f32x4;

// pack two floats -> two fp16 (RNE) in a u32 (low half = a)
__device__ inline unsigned pkh2(float a, float b) {
    union { f16x2 h; unsigned u; } c;
    c.h.x = (_Float16)a; c.h.y = (_Float16)b;
    return c.u;
}

// hi/lo fp16 split of 4 floats: hi = rne(v), lo = rne(v - hi)
__device__ inline void splith4(float v0, float v1, float v2, float v3,
                               uint2& hp, uint2& lp) {
    _Float16 h0 = (_Float16)v0, h1 = (_Float16)v1;
    _Float16 h2 = (_Float16)v2, h3 = (_Float16)v3;
    float r0 = v0 - (float)h0, r1 = v1 - (float)h1;
    float r2 = v2 - (float)h2, r3 = v3 - (float)h3;
    union { f16x2 h; unsigned u; } c;
    c.h.x = h0; c.h.y = h1; hp.x = c.u;
    c.h.x = h2; c.h.y = h3; hp.y = c.u;
    lp.x = pkh2(r0, r1); lp.y = pkh2(r2, r3);
}

// hi-only convert of 4 floats -> uint2 (4 fp16)
__device__ inline uint2 cvth4(float v0, float v1, float v2, float v3) {
    uint2 r; r.x = pkh2(v0, v1); r.y = pkh2(v2, v3); return r;
}

// 8 floats (two float4) -> fp16x8 fragment (hi only, in-register)
__device__ inline f16x8 cvt8h(float4 a, float4 b) {
    f16x8 r;
    r[0] = (_Float16)a.x; r[1] = (_Float16)a.y;
    r[2] = (_Float16)a.z; r[3] = (_Float16)a.w;
    r[4] = (_Float16)b.x; r[5] = (_Float16)b.y;
    r[6] = (_Float16)b.z; r[7] = (_Float16)b.w;
    return r;
}

// 16B fragment from 72-B-strided staging rows (two ds_read_b64)
__device__ inline f16x8 ld16(const char* p) {
    union { uint2 a[2]; f16x8 v; } f;
    f.a[0] = *(const uint2*)p;
    f.a[1] = *(const uint2*)(p + 8);
    return f.v;
}
__device__ inline f16x8 ldb128(const char* p) { return *(const f16x8*)p; }

#define MFMAH __builtin_amdgcn_mfma_f32_16x16x32_f16

// OT=128 o-rows per block, 1024 threads (16 waves, 4m x 4n), 1 block/CU
// (LDS-bound). waves_per_eu(4,4): LDS already caps at 4 waves/EU, so let the
// allocator use the full 128-VGPR budget instead of spilling at 64.
__global__ __launch_bounds__(1024)
__attribute__((amdgpu_waves_per_eu(4, 4)))
void tabl_mfma(
    const float* __restrict__ x, const float* __restrict__ W1,
    const float* __restrict__ W, const float* __restrict__ W2,
    const float* __restrict__ alpha, const float* __restrict__ bias,
    float* __restrict__ out)
{
    __shared__ __align__(16) char Eh[OT * 512];        // E-hi / blended-hi, XOR-swizzled
    __shared__ __align__(16) char Bst[2][2][256 * 72]; // [buf][plane hi/lo]
    __shared__ float redm[4][OT];
    __shared__ float reds[4][OT];

    const int tid    = threadIdx.x;
    const int lane16 = tid & 15;
    const int lg     = (tid >> 4) & 3;
    const int wid    = tid >> 6;          // 0..15
    const int wm     = wid >> 2;          // 0..3
    const int wn     = wid & 3;           // 0..3

    // XCD swizzle: both o-halves of a batch land on the same XCD.
    const int bi  = blockIdx.x;
    const int xcd = bi & 7, q = bi >> 3;
    const int b     = xcd + (q >> 1) * 8;
    const int obase = (q & 1) * OT;

    // staging roles
    const int xs_t = tid & 255;           // staged row (t or s)
    const int koct = tid >> 8;            // 0..3 (8 k each)
    const int stO  = xs_t * 72 + koct * 16;
    const int zs = tid & 127, zoct = (tid >> 7) & 7;   // stage-3: 4 k each
    const int stZ  = zs * 72 + zoct * 8;

    // fragment offsets
    const int rArow[2] = { obase + wm * 32 + lane16, obase + wm * 32 + 16 + lane16 };
    const int eR[2]    = { wm * 32 + lane16, wm * 32 + 16 + lane16 };
    const int eBase[2] = { eR[0] * 512, eR[1] * 512 };
    const int eSw[2]   = { (eR[0] & 7) << 4, (eR[1] & 7) << 4 };
    int bOff[4], b3Off[2];
    #pragma unroll
    for (int nt = 0; nt < 4; ++nt) bOff[nt] = (wn * 64 + nt * 16 + lane16) * 72 + lg * 16;
    #pragma unroll
    for (int nt = 0; nt < 2; ++nt) b3Off[nt] = (wn * 32 + nt * 16 + lane16) * 72 + lg * 16;

    // ================= Stage 1: E = W1h @ (xh + xl)  (2-term fp16) =================
    f32x4 Eacc[2][4];
    #pragma unroll
    for (int mt = 0; mt < 2; ++mt)
        #pragma unroll
        for (int nt = 0; nt < 4; ++nt) Eacc[mt][nt] = (f32x4){0.f,0.f,0.f,0.f};

    const float* xcol = x + (size_t)b * (D1_ * T_) + xs_t;
    float xrN[8]; float4 apfC[2][2], apfN[2][2];

    { // prologue: chunk0 -> buf0 (direct), chunk1 -> xrN, A chunk0 -> apfC
        float x0[8];
        #pragma unroll
        for (int j = 0; j < 8; ++j) x0[j] = xcol[(size_t)(koct * 8 + j) * T_];
        #pragma unroll
        for (int mt = 0; mt < 2; ++mt) {
            const float4* ap = (const float4*)(W1 + (size_t)rArow[mt] * D1_ + lg * 8);
            apfC[mt][0] = ap[0]; apfC[mt][1] = ap[1];
        }
        #pragma unroll
        for (int j = 0; j < 8; ++j) xrN[j] = xcol[(size_t)(32 + koct * 8 + j) * T_];
        uint2 hp, lp;
        splith4(x0[0],x0[1],x0[2],x0[3],hp,lp);
        *(uint2*)(Bst[0][0] + stO) = hp; *(uint2*)(Bst[0][1] + stO) = lp;
        splith4(x0[4],x0[5],x0[6],x0[7],hp,lp);
        *(uint2*)(Bst[0][0] + stO + 8) = hp; *(uint2*)(Bst[0][1] + stO + 8) = lp;
    }
    __syncthreads();

    #pragma unroll 2
    for (int c = 0; c < 16; ++c) {
        const int cur = c & 1;
        // (1) A fragments for this chunk; issue A loads for c+1
        f16x8 Ah[2];
        #pragma unroll
        for (int mt = 0; mt < 2; ++mt) Ah[mt] = cvt8h(apfC[mt][0], apfC[mt][1]);
        if (c < 15) {
            #pragma unroll
            for (int mt = 0; mt < 2; ++mt) {
                const float4* ap = (const float4*)(W1 + (size_t)rArow[mt] * D1_ + (c + 1) * 32 + lg * 8);
                apfN[mt][0] = ap[0]; apfN[mt][1] = ap[1];
            }
        }
        // (2) B fragments + MFMA on buf[cur]
        __builtin_amdgcn_s_setprio(1);
        #pragma unroll
        for (int np = 0; np < 2; ++np) {
            f16x8 Bh[2], Bl[2];
            #pragma unroll
            for (int h = 0; h < 2; ++h) {
                Bh[h] = ld16(Bst[cur][0] + bOff[np * 2 + h]);
                Bl[h] = ld16(Bst[cur][1] + bOff[np * 2 + h]);
            }
            #pragma unroll
            for (int mt = 0; mt < 2; ++mt)
                #pragma unroll
                for (int h = 0; h < 2; ++h) {
                    Eacc[mt][np*2+h] = MFMAH(Ah[mt], Bh[h], Eacc[mt][np*2+h], 0,0,0);
                    Eacc[mt][np*2+h] = MFMAH(Ah[mt], Bl[h], Eacc[mt][np*2+h], 0,0,0);
                }
        }
        __builtin_amdgcn_s_setprio(0);
        // (3) convert+write chunk c+1 (data arrived a full chunk ago)
        if (c < 15) {
            uint2 hp, lp;
            splith4(xrN[0],xrN[1],xrN[2],xrN[3],hp,lp);
            *(uint2*)(Bst[cur^1][0] + stO) = hp; *(uint2*)(Bst[cur^1][1] + stO) = lp;
            splith4(xrN[4],xrN[5],xrN[6],xrN[7],hp,lp);
            *(uint2*)(Bst[cur^1][0] + stO + 8) = hp; *(uint2*)(Bst[cur^1][1] + stO + 8) = lp;
        }
        // (4) issue x loads two chunks ahead
        if (c < 14) {
            #pragma unroll
            for (int j = 0; j < 8; ++j)
                xrN[j] = xcol[(size_t)((c + 2) * 32 + koct * 8 + j) * T_];
        }
        #pragma unroll
        for (int mt = 0; mt < 2; ++mt) {
            apfC[mt][0] = apfN[mt][0]; apfC[mt][1] = apfN[mt][1];
        }
        __syncthreads();
    }

    // write E-hi (fp16) to LDS for stage-2/3 A fragments (E stays in regs for blend)
    #pragma unroll
    for (int mt = 0; mt < 2; ++mt)
        #pragma unroll
        for (int nt = 0; nt < 4; ++nt)
            #pragma unroll
            for (int i = 0; i < 4; ++i) {
                int r = wm * 32 + mt * 16 + lg * 4 + i;
                int t = wn * 64 + nt * 16 + lane16;
                union { _Float16 h; unsigned short u; } cc;
                cc.h = (_Float16)Eacc[mt][nt][i];
                *(unsigned short*)(Eh + r * 512 + ((2 * t) ^ ((r & 7) << 4))) = cc.u;
            }

    // ================= Stage 2: S = Eh @ Wh  (fp16 hi-only) =================
    f32x4 Sacc[2][4];
    #pragma unroll
    for (int mt = 0; mt < 2; ++mt)
        #pragma unroll
        for (int nt = 0; nt < 4; ++nt) Sacc[mt][nt] = (f32x4){0.f,0.f,0.f,0.f};

    const float* wcol = W + xs_t;
    float wrN[8];
    { // prologue: chunk0 -> buf0 (direct), chunk1 -> wrN
        float w0[8];
        #pragma unroll
        for (int j = 0; j < 8; ++j) w0[j] = wcol[(size_t)(koct * 8 + j) * T_];
        #pragma unroll
        for (int j = 0; j < 8; ++j) wrN[j] = wcol[(size_t)(32 + koct * 8 + j) * T_];
        *(uint2*)(Bst[0][0] + stO)     = cvth4(w0[0],w0[1],w0[2],w0[3]);
        *(uint2*)(Bst[0][0] + stO + 8) = cvth4(w0[4],w0[5],w0[6],w0[7]);
    }
    __syncthreads();   // also covers E-hi writes before A reads

    #pragma unroll 2
    for (int c = 0; c < 8; ++c) {
        const int cur = c & 1;
        f16x8 Af[2];
        #pragma unroll
        for (int mt = 0; mt < 2; ++mt)
            Af[mt] = ldb128(Eh + eBase[mt] + ((c * 64 + lg * 16) ^ eSw[mt]));
        __builtin_amdgcn_s_setprio(1);
        #pragma unroll
        for (int np = 0; np < 2; ++np) {
            f16x8 Bf[2];
            #pragma unroll
            for (int h = 0; h < 2; ++h) Bf[h] = ld16(Bst[cur][0] + bOff[np * 2 + h]);
            #pragma unroll
            for (int mt = 0; mt < 2; ++mt)
                #pragma unroll
                for (int h = 0; h < 2; ++h)
                    Sacc[mt][np*2+h] = MFMAH(Af[mt], Bf[h], Sacc[mt][np*2+h], 0,0,0);
        }
        __builtin_amdgcn_s_setprio(0);
        if (c < 7) {
            *(uint2*)(Bst[cur^1][0] + stO)     = cvth4(wrN[0],wrN[1],wrN[2],wrN[3]);
            *(uint2*)(Bst[cur^1][0] + stO + 8) = cvth4(wrN[4],wrN[5],wrN[6],wrN[7]);
        }
        if (c < 6) {
            #pragma unroll
            for (int j = 0; j < 8; ++j)
                wrN[j] = wcol[(size_t)((c + 2) * 32 + koct * 8 + j) * T_];
        }
        __syncthreads();
    }

    // ============ row softmax over s (cross-wave) + blend -> Eh ============
    const float a_ = alpha[0];
    float pm[2][4];
    #pragma unroll
    for (int mt = 0; mt < 2; ++mt)
        #pragma unroll
        for (int i = 0; i < 4; ++i) {
            float m = fmaxf(fmaxf(Sacc[mt][0][i], Sacc[mt][1][i]),
                            fmaxf(Sacc[mt][2][i], Sacc[mt][3][i]));
            m = fmaxf(m, __shfl_xor(m, 1));
            m = fmaxf(m, __shfl_xor(m, 2));
            m = fmaxf(m, __shfl_xor(m, 4));
            m = fmaxf(m, __shfl_xor(m, 8));
            float s = 0.f;
            #pragma unroll
            for (int nt = 0; nt < 4; ++nt) {
                float p = __expf(Sacc[mt][nt][i] - m);
                Sacc[mt][nt][i] = p; s += p;
            }
            s += __shfl_xor(s, 1);
            s += __shfl_xor(s, 2);
            s += __shfl_xor(s, 4);
            s += __shfl_xor(s, 8);
            pm[mt][i] = m;
            if (lane16 == 0) {
                int r = wm * 32 + mt * 16 + lg * 4 + i;
                redm[wn][r] = m; reds[wn][r] = s;
            }
        }
    // issue W2 chunk-0/1 loads (hide under softmax finish)
    float zr0[4], zrN[4];
    #pragma unroll
    for (int j = 0; j < 4; ++j) zr0[j] = W2[(size_t)(zoct * 4 + j) * O2_ + zs];
    #pragma unroll
    for (int j = 0; j < 4; ++j) zrN[j] = W2[(size_t)(32 + zoct * 4 + j) * O2_ + zs];
    __syncthreads();

    #pragma unroll
    for (int mt = 0; mt < 2; ++mt)
        #pragma unroll
        for (int i = 0; i < 4; ++i) {
            int r = wm * 32 + mt * 16 + lg * 4 + i;
            float M = fmaxf(fmaxf(redm[0][r], redm[1][r]),
                            fmaxf(redm[2][r], redm[3][r]));
            float den = reds[0][r] * __expf(redm[0][r] - M)
                      + reds[1][r] * __expf(redm[1][r] - M)
                      + reds[2][r] * __expf(redm[2][r] - M)
                      + reds[3][r] * __expf(redm[3][r] - M);
            float sc = __expf(pm[mt][i] - M) / den;
            #pragma unroll
            for (int nt = 0; nt < 4; ++nt) {
                float f = a_ + (1.f - a_) * Sacc[mt][nt][i] * sc;
                float v = Eacc[mt][nt][i] * f;
                int t = wn * 64 + nt * 16 + lane16;
                union { _Float16 h; unsigned short u; } cc;
                cc.h = (_Float16)v;
                *(unsigned short*)(Eh + r * 512 + ((2 * t) ^ ((r & 7) << 4))) = cc.u;
            }
        }
    { // W2 chunk 0 convert+write (hi only) -> buf0
        *(uint2*)(Bst[0][0] + stZ) = cvth4(zr0[0], zr0[1], zr0[2], zr0[3]);
    }
    __syncthreads();

    // ========== Stage 3: Y = blended_h @ W2h + bias (fp16 hi-only) ==========
    f32x4 Yacc[2][2];
    #pragma unroll
    for (int mt = 0; mt < 2; ++mt)
        #pragma unroll
        for (int nt = 0; nt < 2; ++nt) Yacc[mt][nt] = (f32x4){0.f,0.f,0.f,0.f};

    #pragma unroll 2
    for (int c = 0; c < 8; ++c) {
        const int cur = c & 1;
        f16x8 Ahf[2];
        #pragma unroll
        for (int mt = 0; mt < 2; ++mt)
            Ahf[mt] = ldb128(Eh + eBase[mt] + ((c * 64 + lg * 16) ^ eSw[mt]));
        __builtin_amdgcn_s_setprio(1);
        {
            f16x8 Bh[2];
            #pragma unroll
            for (int nt = 0; nt < 2; ++nt) Bh[nt] = ld16(Bst[cur][0] + b3Off[nt]);
            #pragma unroll
            for (int mt = 0; mt < 2; ++mt)
                #pragma unroll
                for (int nt = 0; nt < 2; ++nt)
                    Yacc[mt][nt] = MFMAH(Ahf[mt], Bh[nt], Yacc[mt][nt], 0,0,0);
        }
        __builtin_amdgcn_s_setprio(0);
        if (c < 7) {
            *(uint2*)(Bst[cur^1][0] + stZ) = cvth4(zrN[0], zrN[1], zrN[2], zrN[3]);
        }
        if (c < 6) {
            #pragma unroll
            for (int j = 0; j < 4; ++j)
                zrN[j] = W2[(size_t)((c + 2) * 32 + zoct * 4 + j) * O2_ + zs];
        }
        __syncthreads();
    }

    // epilogue: + bias, store pre-softmax Y
    #pragma unroll
    for (int mt = 0; mt < 2; ++mt)
        #pragma unroll
        for (int nt = 0; nt < 2; ++nt)
            #pragma unroll
            for (int i = 0; i < 4; ++i) {
                int o  = obase + wm * 32 + mt * 16 + lg * 4 + i;
                int s2 = wn * 32 + nt * 16 + lane16;
                out[((size_t)b * O1_ + o) * O2_ + s2] =
                    Yacc[mt][nt][i] + bias[(size_t)o * O2_ + s2];
            }
}

// in-place softmax over axis 1 (O1); one block per batch
__global__ __launch_bounds__(256) void softmax_o1(float* __restrict__ out)
{
    __shared__ float sm[2][128], ss[2][128];
    const int b  = blockIdx.x;
    const int s2 = threadIdx.x & 127;
    const int oh = threadIdx.x >> 7;
    float* p = out + (size_t)b * (O1_ * O2_) + s2;
    float m = -INFINITY, s = 0.f;
    #pragma unroll 4
    for (int o = oh * 128; o < oh * 128 + 128; ++o) {
        float v = p[(size_t)o * O2_];
        float mn = fmaxf(m, v);
        s = s * __expf(m - mn) + __expf(v - mn);
        m = mn;
    }
    sm[oh][s2] = m; ss[oh][s2] = s;
    __syncthreads();
    float M = fmaxf(sm[0][s2], sm[1][s2]);
    float S = ss[0][s2] * __expf(sm[0][s2] - M) + ss[1][s2] * __expf(sm[1][s2] - M);
    float inv = 1.f / S;
    #pragma unroll 4
    for (int o = oh * 128; o < oh * 128 + 128; ++o) {
        float v = p[(size_t)o * O2_];
        p[(size_t)o * O2_] = __expf(v - M) * inv;
    }
}

extern "C" void kernel_launch(void* const* d_in, const int* in_sizes, int n_in,
                              void* d_out, int out_size, void* d_ws, size_t ws_size,
                              hipStream_t stream)
{
    const float* x     = (const float*)d_in[0];
    const float* W1    = (const float*)d_in[1];
    const float* W     = (const float*)d_in[2];
    const float* W2    = (const float*)d_in[3];
    const float* alpha = (const float*)d_in[4];
    const float* bias  = (const float*)d_in[5];
    float* out = (float*)d_out;

    tabl_mfma<<<dim3(512), 1024, 0, stream>>>(x, W1, W, W2, alpha, bias, out);
    softmax_o1<<<B_, 256, 0, stream>>>(out);
}